// Round 1
// baseline (58.979 us; speedup 1.0000x reference)
//
#include <hip/hip_runtime.h>

#define N 512
#define D 128
// 1000 * log2(e): sigmoid(x/K) = 1/(1+exp(-x*1000)) = 1/(1+exp2(-x*SCALE))
#define RS_SCALE 1442.6950408889634f

static __device__ __forceinline__ float rcp_fast(float x) {
    return __builtin_amdgcn_rcpf(x);
}
static __device__ __forceinline__ float exp2_fast(float x) {
    return __builtin_amdgcn_exp2f(x);
}

// ---------------- kernel 1: per-row inverse norms ----------------
__global__ __launch_bounds__(256) void map_norm_kernel(
    const float* __restrict__ x, float* __restrict__ invn)
{
    int r = blockIdx.x * blockDim.x + threadIdx.x;
    if (r >= N) return;
    const float4* p = (const float4*)(x + r * D);
    float ss = 0.f;
#pragma unroll
    for (int d = 0; d < D / 4; ++d) {
        float4 v = p[d];
        ss = fmaf(v.x, v.x, ss);
        ss = fmaf(v.y, v.y, ss);
        ss = fmaf(v.z, v.z, ss);
        ss = fmaf(v.w, v.w, ss);
    }
    float nrm = fmaxf(sqrtf(ss), 1e-8f);
    invn[r] = 1.0f / nrm;
}

// ---------------- kernel 2: the O(n^3) AP core ----------------
// one block per row i; 256 threads; each thread owns j = t and j = t+256
__global__ __launch_bounds__(256) void map_main_kernel(
    const float* __restrict__ x, const int* __restrict__ tgt,
    const float* __restrict__ invn, float2* __restrict__ av)
{
    const int i = blockIdx.x;
    const int t = threadIdx.x;

    __shared__ float xi[D];
    __shared__ float2 rg[N];  // [l] = {rs (scaled cos sim), gt}; slot N-1 = pad
    __shared__ float red[8];

    const int ti = tgt[i];
    const float si = invn[i];
    if (t < D) xi[t] = x[i * D + t] * si;
    if (t == 0) rg[N - 1] = make_float2(-1e30f, 0.f);  // pad: contributes s=0
    __syncthreads();

    // similarity row: dots of row i against all rows c
    for (int c = t; c < N; c += 256) {
        const float4* xc = (const float4*)(x + c * D);
        float dot = 0.f;
#pragma unroll
        for (int d = 0; d < D / 4; ++d) {
            float4 v = xc[d];
            dot = fmaf(v.x, xi[4 * d + 0], dot);
            dot = fmaf(v.y, xi[4 * d + 1], dot);
            dot = fmaf(v.z, xi[4 * d + 2], dot);
            dot = fmaf(v.w, xi[4 * d + 3], dot);
        }
        if (c != i) {
            int l = c - (c > i);  // off-diagonal extraction index
            rg[l] = make_float2(dot * invn[c] * RS_SCALE,
                                (tgt[c] == ti) ? 1.f : 0.f);
        }
    }
    __syncthreads();

    // each thread: j1 = t (0..255), j2 = t+256 (256..511; 511 is the pad ->
    // gt=0 so its ap contribution vanishes)
    const float rj1 = rg[t].x, gt1 = rg[t].y;
    const float rj2 = rg[t + 256].x, gt2 = rg[t + 256].y;

    float dsum1 = 0.f, gsum1 = 0.f, dsum2 = 0.f, gsum2 = 0.f;
#pragma unroll 4
    for (int l = 0; l < N; ++l) {
        float2 p = rg[l];  // broadcast read, conflict-free
        // indicator = sigmoid((r_l - r_j)/K) = 1/(1+exp2(rs_j - rs_l))
        float e1 = exp2_fast(rj1 - p.x);
        float e2 = exp2_fast(rj2 - p.x);
        float s1 = rcp_fast(1.f + e1);
        float s2 = rcp_fast(1.f + e2);
        dsum1 += s1;
        dsum2 += s2;
        gsum1 = fmaf(p.y, s1, gsum1);
        gsum2 = fmaf(p.y, s2, gsum2);
    }

    float prec1 = gsum1 * rcp_fast(dsum1 + 0.5f);
    float prec2 = gsum2 * rcp_fast(dsum2 + 0.5f);
    float ap = gt1 * prec1 + gt2 * prec2;  // gt-weighted precision
    float np = gt1 + gt2;                  // num_positives partial

    // block reduction (4 waves)
#pragma unroll
    for (int off = 32; off; off >>= 1) {
        ap += __shfl_down(ap, off);
        np += __shfl_down(np, off);
    }
    int w = t >> 6;
    if ((t & 63) == 0) { red[w * 2] = ap; red[w * 2 + 1] = np; }
    __syncthreads();
    if (t == 0) {
        float A = red[0] + red[2] + red[4] + red[6];
        float P = red[1] + red[3] + red[5] + red[7];
        float apn = (P > 0.f) ? (A / P) : 0.f;
        av[i] = make_float2(apn, (P > 0.f) ? 1.f : 0.f);
    }
}

// ---------------- kernel 3: final scalar ----------------
__global__ __launch_bounds__(256) void map_final_kernel(
    const float2* __restrict__ av, float* __restrict__ out)
{
    int t = threadIdx.x;
    float a = 0.f, v = 0.f;
    for (int k = t; k < N; k += 256) {
        float2 p = av[k];
        a += p.x;
        v += p.y;
    }
#pragma unroll
    for (int off = 32; off; off >>= 1) {
        a += __shfl_down(a, off);
        v += __shfl_down(v, off);
    }
    __shared__ float red[8];
    int w = t >> 6;
    if ((t & 63) == 0) { red[w * 2] = a; red[w * 2 + 1] = v; }
    __syncthreads();
    if (t == 0) {
        float A = red[0] + red[2] + red[4] + red[6];
        float V = red[1] + red[3] + red[5] + red[7];
        out[0] = 1.0f - A / V;
    }
}

extern "C" void kernel_launch(void* const* d_in, const int* in_sizes, int n_in,
                              void* d_out, int out_size, void* d_ws, size_t ws_size,
                              hipStream_t stream) {
    const float* x = (const float*)d_in[0];
    const int* tgt = (const int*)d_in[1];
    float* out = (float*)d_out;

    float* invn = (float*)d_ws;                       // 512 floats
    float2* av = (float2*)((char*)d_ws + 2048);       // 512 float2

    map_norm_kernel<<<(N + 255) / 256, 256, 0, stream>>>(x, invn);
    map_main_kernel<<<N, 256, 0, stream>>>(x, tgt, invn, av);
    map_final_kernel<<<1, 256, 0, stream>>>(av, out);
}

// Round 2
// 46.528 us; speedup vs baseline: 1.2676x; 1.2676x over previous
//
#include <hip/hip_runtime.h>

#define N 512
#define D 128
// 1000 * log2(e): sigmoid(x/K) = 1/(1+exp(-x*1000)) = 1/(1+exp2(-x*SCALE))
#define RS_SCALE 1442.6950408889634f

static __device__ __forceinline__ float rcp_fast(float x) {
    return __builtin_amdgcn_rcpf(x);
}
static __device__ __forceinline__ float exp2_fast(float x) {
    return __builtin_amdgcn_exp2f(x);
}

// ---------------- kernel 1: fused norms + similarity row + O(n^2) AP core ----
// one block per row i; 512 threads; thread t owns column c = t and then
// off-diagonal j = t in the sigmoid phase.
__global__ __launch_bounds__(512) void map_main_kernel(
    const float* __restrict__ x, const int* __restrict__ tgt,
    float2* __restrict__ av)
{
    const int i = blockIdx.x;
    const int t = threadIdx.x;

    __shared__ float xi[D];          // raw row i
    __shared__ float sInvI;          // 1/max(||x_i||, eps)
    __shared__ float2 rg[N];         // [l] = {rs scaled sim, gt}; slot 511 = pad
    __shared__ float red[16];

    const int ti = tgt[i];
    if (t < D) xi[t] = x[i * D + t];
    __syncthreads();

    // ---- phase B: dot(x_i, x_c) and ss = ||x_c||^2, c = t ----
    const int c = t;
    {
        const float4* xc = (const float4*)(x + c * D);
        float dot = 0.f, ss = 0.f;
#pragma unroll 8
        for (int d = 0; d < D / 4; ++d) {
            float4 v = xc[d];
            dot = fmaf(v.x, xi[4 * d + 0], dot);
            dot = fmaf(v.y, xi[4 * d + 1], dot);
            dot = fmaf(v.z, xi[4 * d + 2], dot);
            dot = fmaf(v.w, xi[4 * d + 3], dot);
            ss = fmaf(v.x, v.x, ss);
            ss = fmaf(v.y, v.y, ss);
            ss = fmaf(v.z, v.z, ss);
            ss = fmaf(v.w, v.w, ss);
        }
        if (c == i) {
            // for the diagonal thread, dot == ss == ||x_i||^2
            sInvI = rcp_fast(fmaxf(sqrtf(ss), 1e-8f));
            rg[N - 1] = make_float2(-1e30f, 0.f);  // pad slot
        }
        __syncthreads();
        if (c != i) {
            float invc = rcp_fast(fmaxf(sqrtf(ss), 1e-8f));
            int l = c - (c > i);  // off-diagonal extraction index
            rg[l] = make_float2(dot * invc * sInvI * RS_SCALE,
                                (tgt[c] == ti) ? 1.f : 0.f);
        }
    }
    __syncthreads();

    // ---- phase D: j = t; accumulate sigmoids over all l ----
    const float rj = rg[t].x;
    const float gtj = rg[t].y;

    const float4* rg4 = (const float4*)rg;  // 2 l-values per b128 read
    float dsum = 0.f, gsum = 0.f;
#pragma unroll 8
    for (int l4 = 0; l4 < N / 2; ++l4) {
        float4 p = rg4[l4];  // {rs_l0, gt_l0, rs_l1, gt_l1} broadcast
        // indicator = sigmoid((r_l - r_j)/K) = 1/(1+exp2(rs_j - rs_l))
        float e1 = exp2_fast(rj - p.x);
        float e2 = exp2_fast(rj - p.z);
        float s1 = rcp_fast(1.f + e1);
        float s2 = rcp_fast(1.f + e2);
        dsum += s1 + s2;
        gsum = fmaf(p.y, s1, gsum);
        gsum = fmaf(p.w, s2, gsum);
    }

    float prec = gsum * rcp_fast(dsum + 0.5f);
    float ap = gtj * prec;  // gt-weighted precision (pad thread: gtj=0)
    float np = gtj;

    // block reduction (8 waves)
#pragma unroll
    for (int off = 32; off; off >>= 1) {
        ap += __shfl_down(ap, off);
        np += __shfl_down(np, off);
    }
    int w = t >> 6;
    if ((t & 63) == 0) { red[w * 2] = ap; red[w * 2 + 1] = np; }
    __syncthreads();
    if (t == 0) {
        float A = 0.f, P = 0.f;
#pragma unroll
        for (int k = 0; k < 8; ++k) { A += red[2 * k]; P += red[2 * k + 1]; }
        float apn = (P > 0.f) ? (A * rcp_fast(P)) : 0.f;
        av[i] = make_float2(apn, (P > 0.f) ? 1.f : 0.f);
    }
}

// ---------------- kernel 2: final scalar ----------------
__global__ __launch_bounds__(256) void map_final_kernel(
    const float2* __restrict__ av, float* __restrict__ out)
{
    int t = threadIdx.x;
    float a = 0.f, v = 0.f;
    for (int k = t; k < N; k += 256) {
        float2 p = av[k];
        a += p.x;
        v += p.y;
    }
#pragma unroll
    for (int off = 32; off; off >>= 1) {
        a += __shfl_down(a, off);
        v += __shfl_down(v, off);
    }
    __shared__ float red[8];
    int w = t >> 6;
    if ((t & 63) == 0) { red[w * 2] = a; red[w * 2 + 1] = v; }
    __syncthreads();
    if (t == 0) {
        float A = red[0] + red[2] + red[4] + red[6];
        float V = red[1] + red[3] + red[5] + red[7];
        out[0] = 1.0f - A / V;
    }
}

extern "C" void kernel_launch(void* const* d_in, const int* in_sizes, int n_in,
                              void* d_out, int out_size, void* d_ws, size_t ws_size,
                              hipStream_t stream) {
    const float* x = (const float*)d_in[0];
    const int* tgt = (const int*)d_in[1];
    float* out = (float*)d_out;

    float2* av = (float2*)d_ws;  // 512 float2

    map_main_kernel<<<N, 512, 0, stream>>>(x, tgt, av);
    map_final_kernel<<<1, 256, 0, stream>>>(av, out);
}